// Round 16
// baseline (249.273 us; speedup 1.0000x reference)
//
#include <hip/hip_runtime.h>
#include <hip/hip_bf16.h>

// Problem constants (fixed by the reference)
#define T_SEQ 4096
#define C_EMB 768
#define NH_ 12
#define HS_ 64
#define B_SZ 2
#define M_TOK 8192        // B*T
#define N_QKV 2304        // 3*C

typedef __attribute__((ext_vector_type(8))) __bf16 bf16x8;
typedef __attribute__((ext_vector_type(8))) unsigned short ushort8v;
typedef __attribute__((ext_vector_type(2))) unsigned int uint2v;
typedef __attribute__((ext_vector_type(4))) unsigned int uint4v;
typedef __attribute__((ext_vector_type(4))) float f32x4;

__device__ __forceinline__ unsigned short f2bf(float f) {
  __hip_bfloat16 h = __float2bfloat16(f);
  return __builtin_bit_cast(unsigned short, h);
}

// single-instruction packed fp32->bf16 (RNE); S0 -> low half, S1 -> high half
__device__ __forceinline__ unsigned int cvtpk(float lo, float hi) {
  unsigned int r;
  asm("v_cvt_pk_bf16_f32 %0, %1, %2" : "=v"(r) : "v"(lo), "v"(hi));
  return r;
}

// guaranteed single-instruction 2^x (v_exp_f32)
__device__ __forceinline__ float fast_exp2(float x) {
  float r;
  asm("v_exp_f32 %0, %1" : "=v"(r) : "v"(x));
  return r;
}

// async global->LDS, 16B per lane (GEMM staging)
#define GLOAD_LDS16(gp, lp)                                                   \
  __builtin_amdgcn_global_load_lds(                                           \
      (const __attribute__((address_space(1))) void*)(gp),                    \
      (__attribute__((address_space(3))) void*)(lp), 16, 0, 0)

// XOR swizzle for row-major [R][64] bf16 tiles (128 B rows).
#define KSWZ(row, bytecol) ((((row) * 128) + ((bytecol) ^ (((row) & 7) << 4))))

#define LOG2E 1.4426950408889634f

// ---------------------------------------------------------------- converts
#define CVT_N0 (M_TOK * C_EMB)            // x      : 6291456
#define CVT_N1 (N_QKV * C_EMB)            // w_attn : 1769472
#define CVT_N2 (C_EMB * C_EMB)            // w_proj :  589824
__global__ void cvt_all_bf16(const float* __restrict__ x,
                             const float* __restrict__ wa,
                             const float* __restrict__ wp,
                             unsigned short* __restrict__ out) {
  int i = (blockIdx.x * 256 + threadIdx.x) * 8;
  const float* src;
  int j;
  if (i < CVT_N0) { src = x; j = i; }
  else if (i < CVT_N0 + CVT_N1) { src = wa; j = i - CVT_N0; }
  else { src = wp; j = i - CVT_N0 - CVT_N1; }
  float4 a = *reinterpret_cast<const float4*>(&src[j]);
  float4 b = *reinterpret_cast<const float4*>(&src[j + 4]);
  uint4v o;
  o.x = cvtpk(a.x, a.y);
  o.y = cvtpk(a.z, a.w);
  o.z = cvtpk(b.x, b.y);
  o.w = cvtpk(b.z, b.w);
  *reinterpret_cast<uint4v*>(&out[i]) = o;
}

// ---------------------------------------------------------------- GEMM (B^T)
// (R8/R14-proven) C[M][N] = A[M][K] * Bw[N][K]^T + bias. BM x BN tile,
// 4 waves, BK=64, global_load_lds staging with source-side XOR swizzle,
// XCD-aware blockIdx swizzle (requires nwg % 8 == 0).
template <int MODE, int BM, int BN>
__global__ __launch_bounds__(256) void gemm_bt_kernel(
    const unsigned short* __restrict__ A, const unsigned short* __restrict__ Bw,
    const float* __restrict__ bias, unsigned short* __restrict__ qo,
    unsigned short* __restrict__ ko, unsigned short* __restrict__ vo,
    float* __restrict__ fo, int Kdim, int Ndim) {
  constexpr int MF = BM / 32;
  constexpr int NF = BN / 32;
  __shared__ __align__(16) char as_[BM * 128];
  __shared__ __align__(16) char bs_[BN * 128];
  const int tid = threadIdx.x;
  const int lane = tid & 63;
  const int wid = tid >> 6;
  const int g = lane >> 4;
  const int l15 = lane & 15;

  // XCD-aware swizzle: contiguous chunk of blocks per XCD (bijective: nwg%8==0)
  const int nwg = gridDim.x * gridDim.y;
  const int bid = blockIdx.y * gridDim.x + blockIdx.x;
  const int swz = (bid & 7) * (nwg >> 3) + (bid >> 3);
  const int bx = swz % gridDim.x;
  const int by = swz / gridDim.x;

  const int m0 = by * BM;
  const int n0 = bx * BN;
  const int wm = (wid >> 1) * (BM / 2);
  const int wn = (wid & 1) * (BN / 2);

  const int lrow = lane >> 3;
  const int scol = ((lane & 7) ^ lrow) * 8;

  f32x4 acc[MF][NF];
#pragma unroll
  for (int i = 0; i < MF; ++i)
#pragma unroll
    for (int j = 0; j < NF; ++j) acc[i][j] = (f32x4){0.f, 0.f, 0.f, 0.f};

  for (int k0 = 0; k0 < Kdim; k0 += 64) {
#pragma unroll
    for (int i = 0; i < BM / 32; ++i) {
      const int r = wid * (BM / 4) + i * 8 + lrow;
      GLOAD_LDS16(&A[(size_t)(m0 + r) * Kdim + k0 + scol],
                  as_ + wid * (BM * 32) + i * 1024);
    }
#pragma unroll
    for (int i = 0; i < BN / 32; ++i) {
      const int r = wid * (BN / 4) + i * 8 + lrow;
      GLOAD_LDS16(&Bw[(size_t)(n0 + r) * Kdim + k0 + scol],
                  bs_ + wid * (BN * 32) + i * 1024);
    }
    __syncthreads();
#pragma unroll
    for (int ks = 0; ks < 2; ++ks) {
      bf16x8 af[MF], bfr[NF];
#pragma unroll
      for (int mf = 0; mf < MF; ++mf) {
        const int ra = wm + mf * 16 + l15;
        af[mf] = __builtin_bit_cast(bf16x8,
            *reinterpret_cast<const ushort8v*>(as_ + KSWZ(ra, ks * 64 + g * 16)));
      }
#pragma unroll
      for (int nf = 0; nf < NF; ++nf) {
        const int rb = wn + nf * 16 + l15;
        bfr[nf] = __builtin_bit_cast(bf16x8,
            *reinterpret_cast<const ushort8v*>(bs_ + KSWZ(rb, ks * 64 + g * 16)));
      }
#pragma unroll
      for (int mf = 0; mf < MF; ++mf)
#pragma unroll
        for (int nf = 0; nf < NF; ++nf)
          acc[mf][nf] = __builtin_amdgcn_mfma_f32_16x16x32_bf16(
              af[mf], bfr[nf], acc[mf][nf], 0, 0, 0);
    }
    __syncthreads();
  }

#pragma unroll
  for (int mf = 0; mf < MF; ++mf)
#pragma unroll
    for (int nf = 0; nf < NF; ++nf) {
      const int n = n0 + wn + nf * 16 + l15;
      const float bval = bias[n];
      float v4[4];
#pragma unroll
      for (int r2 = 0; r2 < 4; ++r2) v4[r2] = acc[mf][nf][r2] + bval;
      const int mb = m0 + wm + mf * 16 + g * 4;
      if (MODE == 1) {
#pragma unroll
        for (int r2 = 0; r2 < 4; ++r2)
          fo[(size_t)(mb + r2) * Ndim + n] = v4[r2];
      } else {
        const int which = (n >= 1536) ? 2 : ((n >= 768) ? 1 : 0);
        const int c = n - which * 768;
        const int h = c >> 6, d = c & 63;
        const int bI = mb >> 12, t = mb & 4095;
        if (which == 0) {
          const size_t off = ((size_t)(bI * NH_ + h) * T_SEQ + t) * HS_ + d;
#pragma unroll
          for (int r2 = 0; r2 < 4; ++r2)
            qo[off + (size_t)r2 * HS_] = f2bf(v4[r2] * 0.125f);  // fold SCALE
        } else if (which == 1) {
          const size_t off = ((size_t)(bI * NH_ + h) * T_SEQ + t) * HS_ + d;
#pragma unroll
          for (int r2 = 0; r2 < 4; ++r2)
            ko[off + (size_t)r2 * HS_] = f2bf(v4[r2]);
        } else {
          const size_t off = ((size_t)(bI * NH_ + h) * HS_ + d) * T_SEQ + t;
          uint2v o;
          o.x = cvtpk(v4[0], v4[1]);
          o.y = cvtpk(v4[2], v4[3]);
          *reinterpret_cast<uint2v*>(&vo[off]) = o;
        }
      }
    }
}

// ---------------------------------------------------------------- flash attn
// v15 = v10 with pls shrunk 16KB->8KB (two-pass nf: pack+write P^T for one
// nf-half, PV it, reuse the same wave-private 2KB region for the other).
// LDS 40960 B -> 4 blocks/CU (16 waves, +33% latency hiding). vt frags
// re-read per nf (+8 b128/tile-wave; LDS pipe is ~17% utilized). All other
// structure/math identical to v10 (89.6us proven).
__global__ __launch_bounds__(256, 4) void flash_kernel(
    const unsigned short* __restrict__ Qg, const unsigned short* __restrict__ Kg,
    const unsigned short* __restrict__ Vtg, unsigned short* __restrict__ Og) {
  __shared__ __align__(16) char ksm[2][8192];  // K tile [64 tk][64 d], swizzled
  __shared__ __align__(16) char vtm[2][8192];  // Vt tile [64 d][64 tk], swizzled
  __shared__ __align__(16) char pls[8192];     // P^T per wave [16 tq][64 tk]
  const int tid = threadIdx.x;
  const int lane = tid & 63;
  const int wid = tid >> 6;        // 0..3
  const int g = lane >> 4;
  const int l15 = lane & 15;

  // balanced triple mapping: resident triples have ~const qt-sum; heavy first.
  const int cc = blockIdx.x & 255, kk = blockIdx.x >> 8;
  const int m = (kk == 0) ? (767 - cc) : ((kk == 1) ? (256 + cc) : cc);
  const int qt = m / 24;
  const int bh = m - qt * 24;
  const int q0 = qt * 128;
  const int b_ = bh / NH_, h_ = bh % NH_;
  const size_t kqbase = (size_t)bh * T_SEQ * HS_;
  const size_t vtbase = (size_t)bh * HS_ * T_SEQ;
  const int wq0 = wid * 32;

  // Q fragments: loop-invariant, straight from global (no LDS)
  bf16x8 qf[2][2];   // [nf][ks]
#pragma unroll
  for (int nf = 0; nf < 2; ++nf)
#pragma unroll
    for (int ks = 0; ks < 2; ++ks)
      qf[nf][ks] = __builtin_bit_cast(bf16x8,
          *reinterpret_cast<const ushort8v*>(
              &Qg[kqbase + (size_t)(q0 + wq0 + nf * 16 + l15) * HS_ + ks * 32 + g * 8]));

  // all-ones A-fragment for the l (denominator) MFMA
  ushort8v ou;
#pragma unroll
  for (int j = 0; j < 8; ++j) ou[j] = 0x3f80;  // bf16 1.0
  const bf16x8 ones_f = __builtin_bit_cast(bf16x8, ou);

  float m_run[2] = {-1e30f, -1e30f};
  float ml2[2] = {-1.4427e30f, -1.4427e30f};   // m_run * LOG2E
  f32x4 oacc[2][4];
  f32x4 lacc[2];
#pragma unroll
  for (int nf = 0; nf < 2; ++nf) {
    lacc[nf] = (f32x4){0.f, 0.f, 0.f, 0.f};
#pragma unroll
    for (int j = 0; j < 4; ++j) oacc[nf][j] = (f32x4){0.f, 0.f, 0.f, 0.f};
  }

  char* pw = pls + wid * 2048;     // this wave's P^T region [16 tq][64 tk]

  const int nkt = 2 * qt + 2;                    // block KV-tile count
  const int myt = ((q0 + wq0 + 31) >> 6) + 1;    // this wave's needed tiles

  // staging: 256 threads x 2 chunks of 16B for K and for Vt
  int sr[2], sc[2];
  const unsigned short* kgp[2];
  const unsigned short* vgp[2];
#pragma unroll
  for (int it = 0; it < 2; ++it) {
    int ci = tid + it * 256;
    sr[it] = ci >> 3;
    sc[it] = (ci & 7) * 16;
    kgp[it] = &Kg[kqbase + (size_t)sr[it] * HS_ + (sc[it] >> 1)];
    vgp[it] = &Vtg[vtbase + (size_t)sr[it] * T_SEQ + (sc[it] >> 1)];
  }

  ushort8v kreg[2], vreg[2];
#pragma unroll
  for (int it = 0; it < 2; ++it) {               // tile 0
    kreg[it] = *reinterpret_cast<const ushort8v*>(kgp[it]);
    vreg[it] = *reinterpret_cast<const ushort8v*>(vgp[it]);
  }
#pragma unroll
  for (int it = 0; it < 2; ++it) {               // write buf0 (pre-loop)
    *reinterpret_cast<ushort8v*>(&ksm[0][KSWZ(sr[it], sc[it])]) = kreg[it];
    *reinterpret_cast<ushort8v*>(&vtm[0][KSWZ(sr[it], sc[it])]) = vreg[it];
  }
  if (nkt > 1) {                                 // prefetch tile 1
#pragma unroll
    for (int it = 0; it < 2; ++it) {
      kreg[it] = *reinterpret_cast<const ushort8v*>(kgp[it] + (size_t)64 * HS_);
      vreg[it] = *reinterpret_cast<const ushort8v*>(vgp[it] + 64);
    }
  }

  for (int kt = 0; kt < nkt; ++kt) {
    __syncthreads();       // buf[kt&1] writes (prev iter / prologue) visible;
                           // all waves done reading buf[(kt&1)^1]
    const int cur = kt & 1;
    if (kt + 1 < nkt) {
      // stage tile kt+1 into the buffer the block just finished reading
#pragma unroll
      for (int it = 0; it < 2; ++it) {
        *reinterpret_cast<ushort8v*>(&ksm[cur ^ 1][KSWZ(sr[it], sc[it])]) = kreg[it];
        *reinterpret_cast<ushort8v*>(&vtm[cur ^ 1][KSWZ(sr[it], sc[it])]) = vreg[it];
      }
      if (kt + 2 < nkt) {  // prefetch tile kt+2 (in flight over compute)
        const int k2 = (kt + 2) << 6;
#pragma unroll
        for (int it = 0; it < 2; ++it) {
          kreg[it] = *reinterpret_cast<const ushort8v*>(kgp[it] + (size_t)k2 * HS_);
          vreg[it] = *reinterpret_cast<const ushort8v*>(vgp[it] + k2);
        }
      }
    }

    if (kt < myt) {
      const int k0 = kt << 6;
      const char* kb = ksm[cur];
      const char* vb = vtm[cur];

      // ---- QK^T (swapped): St[tk][tq], col tq = nf*16 + l15
      f32x4 st[4][2];
#pragma unroll
      for (int i = 0; i < 4; ++i)
#pragma unroll
        for (int j = 0; j < 2; ++j) st[i][j] = (f32x4){0.f, 0.f, 0.f, 0.f};
#pragma unroll
      for (int ks = 0; ks < 2; ++ks) {
        bf16x8 kf[4];
#pragma unroll
        for (int mf = 0; mf < 4; ++mf)
          kf[mf] = __builtin_bit_cast(bf16x8,
              *reinterpret_cast<const ushort8v*>(
                  kb + KSWZ(mf * 16 + l15, ks * 64 + g * 16)));
#pragma unroll
        for (int mf = 0; mf < 4; ++mf)
#pragma unroll
          for (int nf = 0; nf < 2; ++nf)
            st[mf][nf] = __builtin_amdgcn_mfma_f32_16x16x32_bf16(
                kf[mf], qf[nf][ks], st[mf][nf], 0, 0, 0);
      }

      // ---- causal mask (wave-uniform branch; ~1 diagonal tile per wave)
      if (k0 + 63 > q0 + wq0) {
#pragma unroll
        for (int mf = 0; mf < 4; ++mf)
#pragma unroll
          for (int nf = 0; nf < 2; ++nf) {
            const int tq = q0 + wq0 + nf * 16 + l15;
#pragma unroll
            for (int r2 = 0; r2 < 4; ++r2) {
              const int tk = k0 + mf * 16 + g * 4 + r2;
              if (tk > tq) st[mf][nf][r2] = -1e30f;
            }
          }
      }

      // ---- column max per nf (15 fmax + 2 shfl), then joint defer-max
      float mx[2];
#pragma unroll
      for (int nf = 0; nf < 2; ++nf) {
        float v = fmaxf(fmaxf(st[0][nf][0], st[0][nf][1]),
                        fmaxf(st[0][nf][2], st[0][nf][3]));
        v = fmaxf(v, fmaxf(fmaxf(st[1][nf][0], st[1][nf][1]),
                           fmaxf(st[1][nf][2], st[1][nf][3])));
        v = fmaxf(v, fmaxf(fmaxf(st[2][nf][0], st[2][nf][1]),
                           fmaxf(st[2][nf][2], st[2][nf][3])));
        v = fmaxf(v, fmaxf(fmaxf(st[3][nf][0], st[3][nf][1]),
                           fmaxf(st[3][nf][2], st[3][nf][3])));
        v = fmaxf(v, __shfl_xor(v, 16));
        v = fmaxf(v, __shfl_xor(v, 32));
        mx[nf] = v;
      }
      if (__any((mx[0] > m_run[0] + 8.f) || (mx[1] > m_run[1] + 8.f))) {
#pragma unroll
        for (int nf = 0; nf < 2; ++nf) {
          const float mnew = fmaxf(m_run[nf], mx[nf]);
          const float alpha = fast_exp2((m_run[nf] - mnew) * LOG2E);
#pragma unroll
          for (int nd = 0; nd < 4; ++nd)
#pragma unroll
            for (int r2 = 0; r2 < 4; ++r2) oacc[nf][nd][r2] *= alpha;
#pragma unroll
          for (int r2 = 0; r2 < 4; ++r2) lacc[nf][r2] *= alpha;
          m_run[nf] = mnew;
          ml2[nf] = mnew * LOG2E;
        }
      }

      // ---- two-pass P/PV per nf: pack+write P^T[nf] into the wave's 2KB
      //      region, read pf + vt, MFMA; region reused for the next nf
      //      (wave-private LDS, in-order per-wave ds ops — same reuse
      //      pattern as across kt iterations in v10).
#pragma unroll
      for (int nf = 0; nf < 2; ++nf) {
#pragma unroll
        for (int mf = 0; mf < 4; ++mf) {
          const float p0 = fast_exp2(fmaf(st[mf][nf][0], LOG2E, -ml2[nf]));
          const float p1 = fast_exp2(fmaf(st[mf][nf][1], LOG2E, -ml2[nf]));
          const float p2 = fast_exp2(fmaf(st[mf][nf][2], LOG2E, -ml2[nf]));
          const float p3 = fast_exp2(fmaf(st[mf][nf][3], LOG2E, -ml2[nf]));
          uint2v w;
          w.x = cvtpk(p0, p1);
          w.y = cvtpk(p2, p3);
          *reinterpret_cast<uint2v*>(
              pw + KSWZ(l15, mf * 32 + g * 8)) = w;
        }
#pragma unroll
        for (int ks = 0; ks < 2; ++ks) {
          bf16x8 pf = __builtin_bit_cast(bf16x8,
              *reinterpret_cast<const ushort8v*>(
                  pw + KSWZ(l15, ks * 64 + g * 16)));
          bf16x8 vt[4];
#pragma unroll
          for (int nd = 0; nd < 4; ++nd)
            vt[nd] = __builtin_bit_cast(bf16x8,
                *reinterpret_cast<const ushort8v*>(
                    vb + KSWZ(nd * 16 + l15, ks * 64 + g * 16)));
#pragma unroll
          for (int nd = 0; nd < 4; ++nd)
            oacc[nf][nd] = __builtin_amdgcn_mfma_f32_16x16x32_bf16(
                vt[nd], pf, oacc[nf][nd], 0, 0, 0);
          lacc[nf] = __builtin_amdgcn_mfma_f32_16x16x32_bf16(
              ones_f, pf, lacc[nf], 0, 0, 0);
        }
      }
    }
  }

  // ---- epilogue: normalize per-lane (col=tq), store O^T -> Og[t][c]
#pragma unroll
  for (int nf = 0; nf < 2; ++nf) {
    const float invl = 1.f / lacc[nf][0];
    const int t = q0 + wq0 + nf * 16 + l15;
#pragma unroll
    for (int nd = 0; nd < 4; ++nd) {
      uint2v o;
      o.x = cvtpk(oacc[nf][nd][0] * invl, oacc[nf][nd][1] * invl);
      o.y = cvtpk(oacc[nf][nd][2] * invl, oacc[nf][nd][3] * invl);
      *reinterpret_cast<uint2v*>(
          &Og[((size_t)(b_ * T_SEQ + t)) * C_EMB + h_ * 64 + nd * 16 + g * 4]) = o;
    }
  }
}

// ---------------------------------------------------------------- launch
extern "C" void kernel_launch(void* const* d_in, const int* in_sizes, int n_in,
                              void* d_out, int out_size, void* d_ws, size_t ws_size,
                              hipStream_t stream) {
  const float* x = (const float*)d_in[0];
  const float* w_attn = (const float*)d_in[1];
  const float* b_attn = (const float*)d_in[2];
  const float* w_proj = (const float*)d_in[3];
  const float* b_proj = (const float*)d_in[4];
  float* out = (float*)d_out;

  char* ws = (char*)d_ws;
  size_t off = 0;
  auto carve = [&](size_t bytes) -> void* {
    void* p = ws + off;
    off += (bytes + 255) & ~(size_t)255;
    return p;
  };
  // xbf/wab/wpb must stay contiguous (cvt_all_bf16 writes one range)
  unsigned short* xbf = (unsigned short*)carve((size_t)M_TOK * C_EMB * 2);
  unsigned short* wab = (unsigned short*)carve((size_t)N_QKV * C_EMB * 2);
  unsigned short* wpb = (unsigned short*)carve((size_t)C_EMB * C_EMB * 2);
  unsigned short* Qb = (unsigned short*)carve((size_t)B_SZ * NH_ * T_SEQ * HS_ * 2);
  unsigned short* Kb = (unsigned short*)carve((size_t)B_SZ * NH_ * T_SEQ * HS_ * 2);
  unsigned short* Vtb = (unsigned short*)carve((size_t)B_SZ * NH_ * T_SEQ * HS_ * 2);
  unsigned short* Ob = (unsigned short*)carve((size_t)M_TOK * C_EMB * 2);

  cvt_all_bf16<<<4224, 256, 0, stream>>>(x, w_attn, w_proj, xbf);

  gemm_bt_kernel<0, 128, 128><<<dim3(N_QKV / 128, M_TOK / 128), 256, 0, stream>>>(
      xbf, wab, b_attn, Qb, Kb, Vtb, nullptr, C_EMB, N_QKV);

  flash_kernel<<<dim3(768), 256, 0, stream>>>(Qb, Kb, Vtb, Ob);

  gemm_bt_kernel<1, 64, 128><<<dim3(C_EMB / 128, M_TOK / 64), 256, 0, stream>>>(
      Ob, wpb, b_proj, nullptr, nullptr, nullptr, out, C_EMB, C_EMB);
}

// Round 17
// 148.572 us; speedup vs baseline: 1.6778x; 1.6778x over previous
//
#include <hip/hip_runtime.h>
#include <hip/hip_bf16.h>

// Problem constants (fixed by the reference)
#define T_SEQ 4096
#define C_EMB 768
#define NH_ 12
#define HS_ 64
#define B_SZ 2
#define M_TOK 8192        // B*T
#define N_QKV 2304        // 3*C

typedef __attribute__((ext_vector_type(8))) __bf16 bf16x8;
typedef __attribute__((ext_vector_type(8))) unsigned short ushort8v;
typedef __attribute__((ext_vector_type(2))) unsigned int uint2v;
typedef __attribute__((ext_vector_type(4))) unsigned int uint4v;
typedef __attribute__((ext_vector_type(4))) float f32x4;

__device__ __forceinline__ unsigned short f2bf(float f) {
  __hip_bfloat16 h = __float2bfloat16(f);
  return __builtin_bit_cast(unsigned short, h);
}

// single-instruction packed fp32->bf16 (RNE); S0 -> low half, S1 -> high half
__device__ __forceinline__ unsigned int cvtpk(float lo, float hi) {
  unsigned int r;
  asm("v_cvt_pk_bf16_f32 %0, %1, %2" : "=v"(r) : "v"(lo), "v"(hi));
  return r;
}

// guaranteed single-instruction 2^x (v_exp_f32)
__device__ __forceinline__ float fast_exp2(float x) {
  float r;
  asm("v_exp_f32 %0, %1" : "=v"(r) : "v"(x));
  return r;
}

// async global->LDS, 16B per lane (GEMM staging)
#define GLOAD_LDS16(gp, lp)                                                   \
  __builtin_amdgcn_global_load_lds(                                           \
      (const __attribute__((address_space(1))) void*)(gp),                    \
      (__attribute__((address_space(3))) void*)(lp), 16, 0, 0)

// XOR swizzle for row-major [R][64] bf16 tiles (128 B rows).
#define KSWZ(row, bytecol) ((((row) * 128) + ((bytecol) ^ (((row) & 7) << 4))))

#define LOG2E 1.4426950408889634f

// ---------------------------------------------------------------- converts
#define CVT_N0 (M_TOK * C_EMB)            // x      : 6291456
#define CVT_N1 (N_QKV * C_EMB)            // w_attn : 1769472
#define CVT_N2 (C_EMB * C_EMB)            // w_proj :  589824
__global__ void cvt_all_bf16(const float* __restrict__ x,
                             const float* __restrict__ wa,
                             const float* __restrict__ wp,
                             unsigned short* __restrict__ out) {
  int i = (blockIdx.x * 256 + threadIdx.x) * 8;
  const float* src;
  int j;
  if (i < CVT_N0) { src = x; j = i; }
  else if (i < CVT_N0 + CVT_N1) { src = wa; j = i - CVT_N0; }
  else { src = wp; j = i - CVT_N0 - CVT_N1; }
  float4 a = *reinterpret_cast<const float4*>(&src[j]);
  float4 b = *reinterpret_cast<const float4*>(&src[j + 4]);
  uint4v o;
  o.x = cvtpk(a.x, a.y);
  o.y = cvtpk(a.z, a.w);
  o.z = cvtpk(b.x, b.y);
  o.w = cvtpk(b.z, b.w);
  *reinterpret_cast<uint4v*>(&out[i]) = o;
}

// ---------------------------------------------------------------- GEMM (B^T)
// (R8/R14-proven) C[M][N] = A[M][K] * Bw[N][K]^T + bias. BM x BN tile,
// 4 waves, BK=64, global_load_lds staging with source-side XOR swizzle,
// XCD-aware blockIdx swizzle (requires nwg % 8 == 0).
template <int MODE, int BM, int BN>
__global__ __launch_bounds__(256) void gemm_bt_kernel(
    const unsigned short* __restrict__ A, const unsigned short* __restrict__ Bw,
    const float* __restrict__ bias, unsigned short* __restrict__ qo,
    unsigned short* __restrict__ ko, unsigned short* __restrict__ vo,
    float* __restrict__ fo, int Kdim, int Ndim) {
  constexpr int MF = BM / 32;
  constexpr int NF = BN / 32;
  __shared__ __align__(16) char as_[BM * 128];
  __shared__ __align__(16) char bs_[BN * 128];
  const int tid = threadIdx.x;
  const int lane = tid & 63;
  const int wid = tid >> 6;
  const int g = lane >> 4;
  const int l15 = lane & 15;

  // XCD-aware swizzle: contiguous chunk of blocks per XCD (bijective: nwg%8==0)
  const int nwg = gridDim.x * gridDim.y;
  const int bid = blockIdx.y * gridDim.x + blockIdx.x;
  const int swz = (bid & 7) * (nwg >> 3) + (bid >> 3);
  const int bx = swz % gridDim.x;
  const int by = swz / gridDim.x;

  const int m0 = by * BM;
  const int n0 = bx * BN;
  const int wm = (wid >> 1) * (BM / 2);
  const int wn = (wid & 1) * (BN / 2);

  const int lrow = lane >> 3;
  const int scol = ((lane & 7) ^ lrow) * 8;

  f32x4 acc[MF][NF];
#pragma unroll
  for (int i = 0; i < MF; ++i)
#pragma unroll
    for (int j = 0; j < NF; ++j) acc[i][j] = (f32x4){0.f, 0.f, 0.f, 0.f};

  for (int k0 = 0; k0 < Kdim; k0 += 64) {
#pragma unroll
    for (int i = 0; i < BM / 32; ++i) {
      const int r = wid * (BM / 4) + i * 8 + lrow;
      GLOAD_LDS16(&A[(size_t)(m0 + r) * Kdim + k0 + scol],
                  as_ + wid * (BM * 32) + i * 1024);
    }
#pragma unroll
    for (int i = 0; i < BN / 32; ++i) {
      const int r = wid * (BN / 4) + i * 8 + lrow;
      GLOAD_LDS16(&Bw[(size_t)(n0 + r) * Kdim + k0 + scol],
                  bs_ + wid * (BN * 32) + i * 1024);
    }
    __syncthreads();
#pragma unroll
    for (int ks = 0; ks < 2; ++ks) {
      bf16x8 af[MF], bfr[NF];
#pragma unroll
      for (int mf = 0; mf < MF; ++mf) {
        const int ra = wm + mf * 16 + l15;
        af[mf] = __builtin_bit_cast(bf16x8,
            *reinterpret_cast<const ushort8v*>(as_ + KSWZ(ra, ks * 64 + g * 16)));
      }
#pragma unroll
      for (int nf = 0; nf < NF; ++nf) {
        const int rb = wn + nf * 16 + l15;
        bfr[nf] = __builtin_bit_cast(bf16x8,
            *reinterpret_cast<const ushort8v*>(bs_ + KSWZ(rb, ks * 64 + g * 16)));
      }
#pragma unroll
      for (int mf = 0; mf < MF; ++mf)
#pragma unroll
        for (int nf = 0; nf < NF; ++nf)
          acc[mf][nf] = __builtin_amdgcn_mfma_f32_16x16x32_bf16(
              af[mf], bfr[nf], acc[mf][nf], 0, 0, 0);
    }
    __syncthreads();
  }

#pragma unroll
  for (int mf = 0; mf < MF; ++mf)
#pragma unroll
    for (int nf = 0; nf < NF; ++nf) {
      const int n = n0 + wn + nf * 16 + l15;
      const float bval = bias[n];
      float v4[4];
#pragma unroll
      for (int r2 = 0; r2 < 4; ++r2) v4[r2] = acc[mf][nf][r2] + bval;
      const int mb = m0 + wm + mf * 16 + g * 4;
      if (MODE == 1) {
#pragma unroll
        for (int r2 = 0; r2 < 4; ++r2)
          fo[(size_t)(mb + r2) * Ndim + n] = v4[r2];
      } else {
        const int which = (n >= 1536) ? 2 : ((n >= 768) ? 1 : 0);
        const int c = n - which * 768;
        const int h = c >> 6, d = c & 63;
        const int bI = mb >> 12, t = mb & 4095;
        if (which == 0) {
          const size_t off = ((size_t)(bI * NH_ + h) * T_SEQ + t) * HS_ + d;
#pragma unroll
          for (int r2 = 0; r2 < 4; ++r2)
            qo[off + (size_t)r2 * HS_] = f2bf(v4[r2] * 0.125f);  // fold SCALE
        } else if (which == 1) {
          const size_t off = ((size_t)(bI * NH_ + h) * T_SEQ + t) * HS_ + d;
#pragma unroll
          for (int r2 = 0; r2 < 4; ++r2)
            ko[off + (size_t)r2 * HS_] = f2bf(v4[r2]);
        } else {
          const size_t off = ((size_t)(bI * NH_ + h) * HS_ + d) * T_SEQ + t;
          uint2v o;
          o.x = cvtpk(v4[0], v4[1]);
          o.y = cvtpk(v4[2], v4[3]);
          *reinterpret_cast<uint2v*>(&vo[off]) = o;
        }
      }
    }
}

// ---------------------------------------------------------------- flash attn
// v10 verbatim (R9-benched 89.6us): 256 threads, 4 waves x 32 tq (QBLK=128),
// KV tiles of 64, 16x16 MFMA, reg-staged dbuf (prefetch crosses barriers in
// registers), 1 barrier/tile, balanced triple mapping.
// St = mfma(K,Q) -> St[tk][tq]; per-lane softmax stats (col tq = lane&15).
// l via ones-MFMA; defer-max (THR=8); v_exp_f32; cvt_pk P-pack;
// PV: O^T = mfma(Vt, P^T) via wave-private swizzled LDS P^T.
__global__ __launch_bounds__(256, 3) void flash_kernel(
    const unsigned short* __restrict__ Qg, const unsigned short* __restrict__ Kg,
    const unsigned short* __restrict__ Vtg, unsigned short* __restrict__ Og) {
  __shared__ __align__(16) char ksm[2][8192];  // K tile [64 tk][64 d], swizzled
  __shared__ __align__(16) char vtm[2][8192];  // Vt tile [64 d][64 tk], swizzled
  __shared__ __align__(16) char pls[16384];    // P^T per wave [32 tq][64 tk]
  const int tid = threadIdx.x;
  const int lane = tid & 63;
  const int wid = tid >> 6;        // 0..3
  const int g = lane >> 4;
  const int l15 = lane & 15;

  // balanced triple mapping: resident triple {767-c, 256+c, c} has qt-sum
  // ~const; heavy tiles dispatched first.
  const int cc = blockIdx.x & 255, kk = blockIdx.x >> 8;
  const int m = (kk == 0) ? (767 - cc) : ((kk == 1) ? (256 + cc) : cc);
  const int qt = m / 24;
  const int bh = m - qt * 24;
  const int q0 = qt * 128;
  const int b_ = bh / NH_, h_ = bh % NH_;
  const size_t kqbase = (size_t)bh * T_SEQ * HS_;
  const size_t vtbase = (size_t)bh * HS_ * T_SEQ;
  const int wq0 = wid * 32;

  // Q fragments: loop-invariant, straight from global (no LDS)
  bf16x8 qf[2][2];   // [nf][ks]
#pragma unroll
  for (int nf = 0; nf < 2; ++nf)
#pragma unroll
    for (int ks = 0; ks < 2; ++ks)
      qf[nf][ks] = __builtin_bit_cast(bf16x8,
          *reinterpret_cast<const ushort8v*>(
              &Qg[kqbase + (size_t)(q0 + wq0 + nf * 16 + l15) * HS_ + ks * 32 + g * 8]));

  // all-ones A-fragment for the l (denominator) MFMA
  ushort8v ou;
#pragma unroll
  for (int j = 0; j < 8; ++j) ou[j] = 0x3f80;  // bf16 1.0
  const bf16x8 ones_f = __builtin_bit_cast(bf16x8, ou);

  float m_run[2] = {-1e30f, -1e30f};
  float ml2[2] = {-1.4427e30f, -1.4427e30f};   // m_run * LOG2E
  f32x4 oacc[2][4];
  f32x4 lacc[2];
#pragma unroll
  for (int nf = 0; nf < 2; ++nf) {
    lacc[nf] = (f32x4){0.f, 0.f, 0.f, 0.f};
#pragma unroll
    for (int j = 0; j < 4; ++j) oacc[nf][j] = (f32x4){0.f, 0.f, 0.f, 0.f};
  }

  char* pw = pls + wid * 4096;     // this wave's P^T region [32][64]

  const int nkt = 2 * qt + 2;                    // block KV-tile count
  const int myt = ((q0 + wq0 + 31) >> 6) + 1;    // this wave's needed tiles

  // staging: 256 threads x 2 chunks of 16B for K and for Vt
  int sr[2], sc[2];
  const unsigned short* kgp[2];
  const unsigned short* vgp[2];
#pragma unroll
  for (int it = 0; it < 2; ++it) {
    int ci = tid + it * 256;
    sr[it] = ci >> 3;
    sc[it] = (ci & 7) * 16;
    kgp[it] = &Kg[kqbase + (size_t)sr[it] * HS_ + (sc[it] >> 1)];
    vgp[it] = &Vtg[vtbase + (size_t)sr[it] * T_SEQ + (sc[it] >> 1)];
  }

  ushort8v kreg[2], vreg[2];
#pragma unroll
  for (int it = 0; it < 2; ++it) {               // tile 0
    kreg[it] = *reinterpret_cast<const ushort8v*>(kgp[it]);
    vreg[it] = *reinterpret_cast<const ushort8v*>(vgp[it]);
  }
#pragma unroll
  for (int it = 0; it < 2; ++it) {               // write buf0 (pre-loop)
    *reinterpret_cast<ushort8v*>(&ksm[0][KSWZ(sr[it], sc[it])]) = kreg[it];
    *reinterpret_cast<ushort8v*>(&vtm[0][KSWZ(sr[it], sc[it])]) = vreg[it];
  }
  if (nkt > 1) {                                 // prefetch tile 1
#pragma unroll
    for (int it = 0; it < 2; ++it) {
      kreg[it] = *reinterpret_cast<const ushort8v*>(kgp[it] + (size_t)64 * HS_);
      vreg[it] = *reinterpret_cast<const ushort8v*>(vgp[it] + 64);
    }
  }

  for (int kt = 0; kt < nkt; ++kt) {
    __syncthreads();       // buf[kt&1] writes (prev iter / prologue) visible;
                           // all waves done reading buf[(kt&1)^1]
    const int cur = kt & 1;
    if (kt + 1 < nkt) {
      // stage tile kt+1 into the buffer the block just finished reading
#pragma unroll
      for (int it = 0; it < 2; ++it) {
        *reinterpret_cast<ushort8v*>(&ksm[cur ^ 1][KSWZ(sr[it], sc[it])]) = kreg[it];
        *reinterpret_cast<ushort8v*>(&vtm[cur ^ 1][KSWZ(sr[it], sc[it])]) = vreg[it];
      }
      if (kt + 2 < nkt) {  // prefetch tile kt+2 (in flight over compute)
        const int k2 = (kt + 2) << 6;
#pragma unroll
        for (int it = 0; it < 2; ++it) {
          kreg[it] = *reinterpret_cast<const ushort8v*>(kgp[it] + (size_t)k2 * HS_);
          vreg[it] = *reinterpret_cast<const ushort8v*>(vgp[it] + k2);
        }
      }
    }

    if (kt < myt) {
      const int k0 = kt << 6;
      const char* kb = ksm[cur];
      const char* vb = vtm[cur];

      // ---- QK^T (swapped): St[tk][tq], col tq = nf*16 + l15
      f32x4 st[4][2];
#pragma unroll
      for (int i = 0; i < 4; ++i)
#pragma unroll
        for (int j = 0; j < 2; ++j) st[i][j] = (f32x4){0.f, 0.f, 0.f, 0.f};
#pragma unroll
      for (int ks = 0; ks < 2; ++ks) {
        bf16x8 kf[4];
#pragma unroll
        for (int mf = 0; mf < 4; ++mf)
          kf[mf] = __builtin_bit_cast(bf16x8,
              *reinterpret_cast<const ushort8v*>(
                  kb + KSWZ(mf * 16 + l15, ks * 64 + g * 16)));
#pragma unroll
        for (int mf = 0; mf < 4; ++mf)
#pragma unroll
          for (int nf = 0; nf < 2; ++nf)
            st[mf][nf] = __builtin_amdgcn_mfma_f32_16x16x32_bf16(
                kf[mf], qf[nf][ks], st[mf][nf], 0, 0, 0);
      }

      // ---- causal mask (wave-uniform branch; ~1 diagonal tile per wave)
      if (k0 + 63 > q0 + wq0) {
#pragma unroll
        for (int mf = 0; mf < 4; ++mf)
#pragma unroll
          for (int nf = 0; nf < 2; ++nf) {
            const int tq = q0 + wq0 + nf * 16 + l15;
#pragma unroll
            for (int r2 = 0; r2 < 4; ++r2) {
              const int tk = k0 + mf * 16 + g * 4 + r2;
              if (tk > tq) st[mf][nf][r2] = -1e30f;
            }
          }
      }

      // ---- column max per nf (15 fmax + 2 shfl), then joint defer-max
      float mx[2];
#pragma unroll
      for (int nf = 0; nf < 2; ++nf) {
        float v = fmaxf(fmaxf(st[0][nf][0], st[0][nf][1]),
                        fmaxf(st[0][nf][2], st[0][nf][3]));
        v = fmaxf(v, fmaxf(fmaxf(st[1][nf][0], st[1][nf][1]),
                           fmaxf(st[1][nf][2], st[1][nf][3])));
        v = fmaxf(v, fmaxf(fmaxf(st[2][nf][0], st[2][nf][1]),
                           fmaxf(st[2][nf][2], st[2][nf][3])));
        v = fmaxf(v, fmaxf(fmaxf(st[3][nf][0], st[3][nf][1]),
                           fmaxf(st[3][nf][2], st[3][nf][3])));
        v = fmaxf(v, __shfl_xor(v, 16));
        v = fmaxf(v, __shfl_xor(v, 32));
        mx[nf] = v;
      }
      if (__any((mx[0] > m_run[0] + 8.f) || (mx[1] > m_run[1] + 8.f))) {
#pragma unroll
        for (int nf = 0; nf < 2; ++nf) {
          const float mnew = fmaxf(m_run[nf], mx[nf]);
          const float alpha = fast_exp2((m_run[nf] - mnew) * LOG2E);
#pragma unroll
          for (int nd = 0; nd < 4; ++nd)
#pragma unroll
            for (int r2 = 0; r2 < 4; ++r2) oacc[nf][nd][r2] *= alpha;
#pragma unroll
          for (int r2 = 0; r2 < 4; ++r2) lacc[nf][r2] *= alpha;
          m_run[nf] = mnew;
          ml2[nf] = mnew * LOG2E;
        }
      }

      // ---- P = exp2(st*LOG2E - ml2); cvt_pk pack; write P^T to wave LDS
#pragma unroll
      for (int mf = 0; mf < 4; ++mf)
#pragma unroll
        for (int nf = 0; nf < 2; ++nf) {
          const float p0 = fast_exp2(fmaf(st[mf][nf][0], LOG2E, -ml2[nf]));
          const float p1 = fast_exp2(fmaf(st[mf][nf][1], LOG2E, -ml2[nf]));
          const float p2 = fast_exp2(fmaf(st[mf][nf][2], LOG2E, -ml2[nf]));
          const float p3 = fast_exp2(fmaf(st[mf][nf][3], LOG2E, -ml2[nf]));
          uint2v w;
          w.x = cvtpk(p0, p1);
          w.y = cvtpk(p2, p3);
          *reinterpret_cast<uint2v*>(
              pw + KSWZ(nf * 16 + l15, mf * 32 + g * 8)) = w;
        }

      // ---- PV: O^T[d][tq] += mfma(Vt, P^T);  l via ones-MFMA
#pragma unroll
      for (int ks = 0; ks < 2; ++ks) {
        bf16x8 pf[2];
#pragma unroll
        for (int nf = 0; nf < 2; ++nf)
          pf[nf] = __builtin_bit_cast(bf16x8,
              *reinterpret_cast<const ushort8v*>(
                  pw + KSWZ(nf * 16 + l15, ks * 64 + g * 16)));
        bf16x8 vt[4];
#pragma unroll
        for (int nd = 0; nd < 4; ++nd)
          vt[nd] = __builtin_bit_cast(bf16x8,
              *reinterpret_cast<const ushort8v*>(
                  vb + KSWZ(nd * 16 + l15, ks * 64 + g * 16)));
#pragma unroll
        for (int nf = 0; nf < 2; ++nf) {
#pragma unroll
          for (int nd = 0; nd < 4; ++nd)
            oacc[nf][nd] = __builtin_amdgcn_mfma_f32_16x16x32_bf16(
                vt[nd], pf[nf], oacc[nf][nd], 0, 0, 0);
          lacc[nf] = __builtin_amdgcn_mfma_f32_16x16x32_bf16(
              ones_f, pf[nf], lacc[nf], 0, 0, 0);
        }
      }
    }
  }

  // ---- epilogue: normalize per-lane (col=tq), store O^T -> Og[t][c]
#pragma unroll
  for (int nf = 0; nf < 2; ++nf) {
    const float invl = 1.f / lacc[nf][0];
    const int t = q0 + wq0 + nf * 16 + l15;
#pragma unroll
    for (int nd = 0; nd < 4; ++nd) {
      uint2v o;
      o.x = cvtpk(oacc[nf][nd][0] * invl, oacc[nf][nd][1] * invl);
      o.y = cvtpk(oacc[nf][nd][2] * invl, oacc[nf][nd][3] * invl);
      *reinterpret_cast<uint2v*>(
          &Og[((size_t)(b_ * T_SEQ + t)) * C_EMB + h_ * 64 + nd * 16 + g * 4]) = o;
    }
  }
}

// ---------------------------------------------------------------- launch
extern "C" void kernel_launch(void* const* d_in, const int* in_sizes, int n_in,
                              void* d_out, int out_size, void* d_ws, size_t ws_size,
                              hipStream_t stream) {
  const float* x = (const float*)d_in[0];
  const float* w_attn = (const float*)d_in[1];
  const float* b_attn = (const float*)d_in[2];
  const float* w_proj = (const float*)d_in[3];
  const float* b_proj = (const float*)d_in[4];
  float* out = (float*)d_out;

  char* ws = (char*)d_ws;
  size_t off = 0;
  auto carve = [&](size_t bytes) -> void* {
    void* p = ws + off;
    off += (bytes + 255) & ~(size_t)255;
    return p;
  };
  // xbf/wab/wpb must stay contiguous (cvt_all_bf16 writes one range)
  unsigned short* xbf = (unsigned short*)carve((size_t)M_TOK * C_EMB * 2);
  unsigned short* wab = (unsigned short*)carve((size_t)N_QKV * C_EMB * 2);
  unsigned short* wpb = (unsigned short*)carve((size_t)C_EMB * C_EMB * 2);
  unsigned short* Qb = (unsigned short*)carve((size_t)B_SZ * NH_ * T_SEQ * HS_ * 2);
  unsigned short* Kb = (unsigned short*)carve((size_t)B_SZ * NH_ * T_SEQ * HS_ * 2);
  unsigned short* Vtb = (unsigned short*)carve((size_t)B_SZ * NH_ * T_SEQ * HS_ * 2);
  unsigned short* Ob = (unsigned short*)carve((size_t)M_TOK * C_EMB * 2);

  cvt_all_bf16<<<4224, 256, 0, stream>>>(x, w_attn, w_proj, xbf);

  gemm_bt_kernel<0, 128, 128><<<dim3(N_QKV / 128, M_TOK / 128), 256, 0, stream>>>(
      xbf, wab, b_attn, Qb, Kb, Vtb, nullptr, C_EMB, N_QKV);

  flash_kernel<<<dim3(768), 256, 0, stream>>>(Qb, Kb, Vtb, Ob);

  gemm_bt_kernel<1, 64, 128><<<dim3(C_EMB / 128, M_TOK / 64), 256, 0, stream>>>(
      Ob, wpb, b_proj, nullptr, nullptr, nullptr, out, C_EMB, C_EMB);
}

// Round 18
// 147.192 us; speedup vs baseline: 1.6935x; 1.0094x over previous
//
#include <hip/hip_runtime.h>
#include <hip/hip_bf16.h>

// Problem constants (fixed by the reference)
#define T_SEQ 4096
#define C_EMB 768
#define NH_ 12
#define HS_ 64
#define B_SZ 2
#define M_TOK 8192        // B*T
#define N_QKV 2304        // 3*C

typedef __attribute__((ext_vector_type(8))) __bf16 bf16x8;
typedef __attribute__((ext_vector_type(8))) unsigned short ushort8v;
typedef __attribute__((ext_vector_type(2))) unsigned int uint2v;
typedef __attribute__((ext_vector_type(4))) unsigned int uint4v;
typedef __attribute__((ext_vector_type(4))) float f32x4;

__device__ __forceinline__ unsigned short f2bf(float f) {
  __hip_bfloat16 h = __float2bfloat16(f);
  return __builtin_bit_cast(unsigned short, h);
}

// single-instruction packed fp32->bf16 (RNE); S0 -> low half, S1 -> high half
__device__ __forceinline__ unsigned int cvtpk(float lo, float hi) {
  unsigned int r;
  asm("v_cvt_pk_bf16_f32 %0, %1, %2" : "=v"(r) : "v"(lo), "v"(hi));
  return r;
}

// guaranteed single-instruction 2^x (v_exp_f32)
__device__ __forceinline__ float fast_exp2(float x) {
  float r;
  asm("v_exp_f32 %0, %1" : "=v"(r) : "v"(x));
  return r;
}

// async global->LDS, 16B per lane (GEMM staging)
#define GLOAD_LDS16(gp, lp)                                                   \
  __builtin_amdgcn_global_load_lds(                                           \
      (const __attribute__((address_space(1))) void*)(gp),                    \
      (__attribute__((address_space(3))) void*)(lp), 16, 0, 0)

// XOR swizzle for row-major [R][64] bf16 tiles (128 B rows).
#define KSWZ(row, bytecol) ((((row) * 128) + ((bytecol) ^ (((row) & 7) << 4))))

#define LOG2E 1.4426950408889634f

// ---------------------------------------------------------------- converts
#define CVT_N0 (M_TOK * C_EMB)            // x      : 6291456
#define CVT_N1 (N_QKV * C_EMB)            // w_attn : 1769472
#define CVT_N2 (C_EMB * C_EMB)            // w_proj :  589824
__global__ void cvt_all_bf16(const float* __restrict__ x,
                             const float* __restrict__ wa,
                             const float* __restrict__ wp,
                             unsigned short* __restrict__ out) {
  int i = (blockIdx.x * 256 + threadIdx.x) * 8;
  const float* src;
  int j;
  if (i < CVT_N0) { src = x; j = i; }
  else if (i < CVT_N0 + CVT_N1) { src = wa; j = i - CVT_N0; }
  else { src = wp; j = i - CVT_N0 - CVT_N1; }
  float4 a = *reinterpret_cast<const float4*>(&src[j]);
  float4 b = *reinterpret_cast<const float4*>(&src[j + 4]);
  uint4v o;
  o.x = cvtpk(a.x, a.y);
  o.y = cvtpk(a.z, a.w);
  o.z = cvtpk(b.x, b.y);
  o.w = cvtpk(b.z, b.w);
  *reinterpret_cast<uint4v*>(&out[i]) = o;
}

// ---------------------------------------------------------------- GEMM (B^T)
// (R8/R14-proven) C[M][N] = A[M][K] * Bw[N][K]^T + bias. BM x BN tile,
// 4 waves, BK=64, global_load_lds staging with source-side XOR swizzle,
// XCD-aware blockIdx swizzle (requires nwg % 8 == 0).
template <int MODE, int BM, int BN>
__global__ __launch_bounds__(256) void gemm_bt_kernel(
    const unsigned short* __restrict__ A, const unsigned short* __restrict__ Bw,
    const float* __restrict__ bias, unsigned short* __restrict__ qo,
    unsigned short* __restrict__ ko, unsigned short* __restrict__ vo,
    float* __restrict__ fo, int Kdim, int Ndim) {
  constexpr int MF = BM / 32;
  constexpr int NF = BN / 32;
  __shared__ __align__(16) char as_[BM * 128];
  __shared__ __align__(16) char bs_[BN * 128];
  const int tid = threadIdx.x;
  const int lane = tid & 63;
  const int wid = tid >> 6;
  const int g = lane >> 4;
  const int l15 = lane & 15;

  // XCD-aware swizzle: contiguous chunk of blocks per XCD (bijective: nwg%8==0)
  const int nwg = gridDim.x * gridDim.y;
  const int bid = blockIdx.y * gridDim.x + blockIdx.x;
  const int swz = (bid & 7) * (nwg >> 3) + (bid >> 3);
  const int bx = swz % gridDim.x;
  const int by = swz / gridDim.x;

  const int m0 = by * BM;
  const int n0 = bx * BN;
  const int wm = (wid >> 1) * (BM / 2);
  const int wn = (wid & 1) * (BN / 2);

  const int lrow = lane >> 3;
  const int scol = ((lane & 7) ^ lrow) * 8;

  f32x4 acc[MF][NF];
#pragma unroll
  for (int i = 0; i < MF; ++i)
#pragma unroll
    for (int j = 0; j < NF; ++j) acc[i][j] = (f32x4){0.f, 0.f, 0.f, 0.f};

  for (int k0 = 0; k0 < Kdim; k0 += 64) {
#pragma unroll
    for (int i = 0; i < BM / 32; ++i) {
      const int r = wid * (BM / 4) + i * 8 + lrow;
      GLOAD_LDS16(&A[(size_t)(m0 + r) * Kdim + k0 + scol],
                  as_ + wid * (BM * 32) + i * 1024);
    }
#pragma unroll
    for (int i = 0; i < BN / 32; ++i) {
      const int r = wid * (BN / 4) + i * 8 + lrow;
      GLOAD_LDS16(&Bw[(size_t)(n0 + r) * Kdim + k0 + scol],
                  bs_ + wid * (BN * 32) + i * 1024);
    }
    __syncthreads();
#pragma unroll
    for (int ks = 0; ks < 2; ++ks) {
      bf16x8 af[MF], bfr[NF];
#pragma unroll
      for (int mf = 0; mf < MF; ++mf) {
        const int ra = wm + mf * 16 + l15;
        af[mf] = __builtin_bit_cast(bf16x8,
            *reinterpret_cast<const ushort8v*>(as_ + KSWZ(ra, ks * 64 + g * 16)));
      }
#pragma unroll
      for (int nf = 0; nf < NF; ++nf) {
        const int rb = wn + nf * 16 + l15;
        bfr[nf] = __builtin_bit_cast(bf16x8,
            *reinterpret_cast<const ushort8v*>(bs_ + KSWZ(rb, ks * 64 + g * 16)));
      }
#pragma unroll
      for (int mf = 0; mf < MF; ++mf)
#pragma unroll
        for (int nf = 0; nf < NF; ++nf)
          acc[mf][nf] = __builtin_amdgcn_mfma_f32_16x16x32_bf16(
              af[mf], bfr[nf], acc[mf][nf], 0, 0, 0);
    }
    __syncthreads();
  }

#pragma unroll
  for (int mf = 0; mf < MF; ++mf)
#pragma unroll
    for (int nf = 0; nf < NF; ++nf) {
      const int n = n0 + wn + nf * 16 + l15;
      const float bval = bias[n];
      float v4[4];
#pragma unroll
      for (int r2 = 0; r2 < 4; ++r2) v4[r2] = acc[mf][nf][r2] + bval;
      const int mb = m0 + wm + mf * 16 + g * 4;
      if (MODE == 1) {
#pragma unroll
        for (int r2 = 0; r2 < 4; ++r2)
          fo[(size_t)(mb + r2) * Ndim + n] = v4[r2];
      } else {
        const int which = (n >= 1536) ? 2 : ((n >= 768) ? 1 : 0);
        const int c = n - which * 768;
        const int h = c >> 6, d = c & 63;
        const int bI = mb >> 12, t = mb & 4095;
        if (which == 0) {
          const size_t off = ((size_t)(bI * NH_ + h) * T_SEQ + t) * HS_ + d;
#pragma unroll
          for (int r2 = 0; r2 < 4; ++r2)
            qo[off + (size_t)r2 * HS_] = f2bf(v4[r2] * 0.125f);  // fold SCALE
        } else if (which == 1) {
          const size_t off = ((size_t)(bI * NH_ + h) * T_SEQ + t) * HS_ + d;
#pragma unroll
          for (int r2 = 0; r2 < 4; ++r2)
            ko[off + (size_t)r2 * HS_] = f2bf(v4[r2]);
        } else {
          const size_t off = ((size_t)(bI * NH_ + h) * HS_ + d) * T_SEQ + t;
          uint2v o;
          o.x = cvtpk(v4[0], v4[1]);
          o.y = cvtpk(v4[2], v4[3]);
          *reinterpret_cast<uint2v*>(&vo[off]) = o;
        }
      }
    }
}

// ---------------------------------------------------------------- flash attn
// v16 = v15 two-pass-nf structure (pls 8KB, LDS total 40960 B -> exactly
// 4 blocks/CU by LDS arithmetic) but with launch_bounds kept at (256,3) so
// the register allocator keeps v10's proven 80-VGPR budget (R15's spill came
// from the (256,4) allocator retarget, not from the LDS shrink).
__global__ __launch_bounds__(256, 3) void flash_kernel(
    const unsigned short* __restrict__ Qg, const unsigned short* __restrict__ Kg,
    const unsigned short* __restrict__ Vtg, unsigned short* __restrict__ Og) {
  __shared__ __align__(16) char ksm[2][8192];  // K tile [64 tk][64 d], swizzled
  __shared__ __align__(16) char vtm[2][8192];  // Vt tile [64 d][64 tk], swizzled
  __shared__ __align__(16) char pls[8192];     // P^T per wave [16 tq][64 tk]
  const int tid = threadIdx.x;
  const int lane = tid & 63;
  const int wid = tid >> 6;        // 0..3
  const int g = lane >> 4;
  const int l15 = lane & 15;

  // balanced triple mapping: resident triples have ~const qt-sum; heavy first.
  const int cc = blockIdx.x & 255, kk = blockIdx.x >> 8;
  const int m = (kk == 0) ? (767 - cc) : ((kk == 1) ? (256 + cc) : cc);
  const int qt = m / 24;
  const int bh = m - qt * 24;
  const int q0 = qt * 128;
  const int b_ = bh / NH_, h_ = bh % NH_;
  const size_t kqbase = (size_t)bh * T_SEQ * HS_;
  const size_t vtbase = (size_t)bh * HS_ * T_SEQ;
  const int wq0 = wid * 32;

  // Q fragments: loop-invariant, straight from global (no LDS)
  bf16x8 qf[2][2];   // [nf][ks]
#pragma unroll
  for (int nf = 0; nf < 2; ++nf)
#pragma unroll
    for (int ks = 0; ks < 2; ++ks)
      qf[nf][ks] = __builtin_bit_cast(bf16x8,
          *reinterpret_cast<const ushort8v*>(
              &Qg[kqbase + (size_t)(q0 + wq0 + nf * 16 + l15) * HS_ + ks * 32 + g * 8]));

  // all-ones A-fragment for the l (denominator) MFMA
  ushort8v ou;
#pragma unroll
  for (int j = 0; j < 8; ++j) ou[j] = 0x3f80;  // bf16 1.0
  const bf16x8 ones_f = __builtin_bit_cast(bf16x8, ou);

  float m_run[2] = {-1e30f, -1e30f};
  float ml2[2] = {-1.4427e30f, -1.4427e30f};   // m_run * LOG2E
  f32x4 oacc[2][4];
  f32x4 lacc[2];
#pragma unroll
  for (int nf = 0; nf < 2; ++nf) {
    lacc[nf] = (f32x4){0.f, 0.f, 0.f, 0.f};
#pragma unroll
    for (int j = 0; j < 4; ++j) oacc[nf][j] = (f32x4){0.f, 0.f, 0.f, 0.f};
  }

  char* pw = pls + wid * 2048;     // this wave's P^T region [16 tq][64 tk]

  const int nkt = 2 * qt + 2;                    // block KV-tile count
  const int myt = ((q0 + wq0 + 31) >> 6) + 1;    // this wave's needed tiles

  // staging: 256 threads x 2 chunks of 16B for K and for Vt
  int sr[2], sc[2];
  const unsigned short* kgp[2];
  const unsigned short* vgp[2];
#pragma unroll
  for (int it = 0; it < 2; ++it) {
    int ci = tid + it * 256;
    sr[it] = ci >> 3;
    sc[it] = (ci & 7) * 16;
    kgp[it] = &Kg[kqbase + (size_t)sr[it] * HS_ + (sc[it] >> 1)];
    vgp[it] = &Vtg[vtbase + (size_t)sr[it] * T_SEQ + (sc[it] >> 1)];
  }

  ushort8v kreg[2], vreg[2];
#pragma unroll
  for (int it = 0; it < 2; ++it) {               // tile 0
    kreg[it] = *reinterpret_cast<const ushort8v*>(kgp[it]);
    vreg[it] = *reinterpret_cast<const ushort8v*>(vgp[it]);
  }
#pragma unroll
  for (int it = 0; it < 2; ++it) {               // write buf0 (pre-loop)
    *reinterpret_cast<ushort8v*>(&ksm[0][KSWZ(sr[it], sc[it])]) = kreg[it];
    *reinterpret_cast<ushort8v*>(&vtm[0][KSWZ(sr[it], sc[it])]) = vreg[it];
  }
  if (nkt > 1) {                                 // prefetch tile 1
#pragma unroll
    for (int it = 0; it < 2; ++it) {
      kreg[it] = *reinterpret_cast<const ushort8v*>(kgp[it] + (size_t)64 * HS_);
      vreg[it] = *reinterpret_cast<const ushort8v*>(vgp[it] + 64);
    }
  }

  for (int kt = 0; kt < nkt; ++kt) {
    __syncthreads();       // buf[kt&1] writes (prev iter / prologue) visible;
                           // all waves done reading buf[(kt&1)^1]
    const int cur = kt & 1;
    if (kt + 1 < nkt) {
      // stage tile kt+1 into the buffer the block just finished reading
#pragma unroll
      for (int it = 0; it < 2; ++it) {
        *reinterpret_cast<ushort8v*>(&ksm[cur ^ 1][KSWZ(sr[it], sc[it])]) = kreg[it];
        *reinterpret_cast<ushort8v*>(&vtm[cur ^ 1][KSWZ(sr[it], sc[it])]) = vreg[it];
      }
      if (kt + 2 < nkt) {  // prefetch tile kt+2 (in flight over compute)
        const int k2 = (kt + 2) << 6;
#pragma unroll
        for (int it = 0; it < 2; ++it) {
          kreg[it] = *reinterpret_cast<const ushort8v*>(kgp[it] + (size_t)k2 * HS_);
          vreg[it] = *reinterpret_cast<const ushort8v*>(vgp[it] + k2);
        }
      }
    }

    if (kt < myt) {
      const int k0 = kt << 6;
      const char* kb = ksm[cur];
      const char* vb = vtm[cur];

      // ---- QK^T (swapped): St[tk][tq], col tq = nf*16 + l15
      f32x4 st[4][2];
#pragma unroll
      for (int i = 0; i < 4; ++i)
#pragma unroll
        for (int j = 0; j < 2; ++j) st[i][j] = (f32x4){0.f, 0.f, 0.f, 0.f};
#pragma unroll
      for (int ks = 0; ks < 2; ++ks) {
        bf16x8 kf[4];
#pragma unroll
        for (int mf = 0; mf < 4; ++mf)
          kf[mf] = __builtin_bit_cast(bf16x8,
              *reinterpret_cast<const ushort8v*>(
                  kb + KSWZ(mf * 16 + l15, ks * 64 + g * 16)));
#pragma unroll
        for (int mf = 0; mf < 4; ++mf)
#pragma unroll
          for (int nf = 0; nf < 2; ++nf)
            st[mf][nf] = __builtin_amdgcn_mfma_f32_16x16x32_bf16(
                kf[mf], qf[nf][ks], st[mf][nf], 0, 0, 0);
      }

      // ---- causal mask (wave-uniform branch; ~1 diagonal tile per wave)
      if (k0 + 63 > q0 + wq0) {
#pragma unroll
        for (int mf = 0; mf < 4; ++mf)
#pragma unroll
          for (int nf = 0; nf < 2; ++nf) {
            const int tq = q0 + wq0 + nf * 16 + l15;
#pragma unroll
            for (int r2 = 0; r2 < 4; ++r2) {
              const int tk = k0 + mf * 16 + g * 4 + r2;
              if (tk > tq) st[mf][nf][r2] = -1e30f;
            }
          }
      }

      // ---- column max per nf (15 fmax + 2 shfl), then joint defer-max
      float mx[2];
#pragma unroll
      for (int nf = 0; nf < 2; ++nf) {
        float v = fmaxf(fmaxf(st[0][nf][0], st[0][nf][1]),
                        fmaxf(st[0][nf][2], st[0][nf][3]));
        v = fmaxf(v, fmaxf(fmaxf(st[1][nf][0], st[1][nf][1]),
                           fmaxf(st[1][nf][2], st[1][nf][3])));
        v = fmaxf(v, fmaxf(fmaxf(st[2][nf][0], st[2][nf][1]),
                           fmaxf(st[2][nf][2], st[2][nf][3])));
        v = fmaxf(v, fmaxf(fmaxf(st[3][nf][0], st[3][nf][1]),
                           fmaxf(st[3][nf][2], st[3][nf][3])));
        v = fmaxf(v, __shfl_xor(v, 16));
        v = fmaxf(v, __shfl_xor(v, 32));
        mx[nf] = v;
      }
      if (__any((mx[0] > m_run[0] + 8.f) || (mx[1] > m_run[1] + 8.f))) {
#pragma unroll
        for (int nf = 0; nf < 2; ++nf) {
          const float mnew = fmaxf(m_run[nf], mx[nf]);
          const float alpha = fast_exp2((m_run[nf] - mnew) * LOG2E);
#pragma unroll
          for (int nd = 0; nd < 4; ++nd)
#pragma unroll
            for (int r2 = 0; r2 < 4; ++r2) oacc[nf][nd][r2] *= alpha;
#pragma unroll
          for (int r2 = 0; r2 < 4; ++r2) lacc[nf][r2] *= alpha;
          m_run[nf] = mnew;
          ml2[nf] = mnew * LOG2E;
        }
      }

      // ---- two-pass P/PV per nf: pack+write P^T[nf] into the wave's 2KB
      //      region, read pf + vt, MFMA; region reused for the next nf
      //      (wave-private LDS, in-order per-wave ds ops).
#pragma unroll
      for (int nf = 0; nf < 2; ++nf) {
#pragma unroll
        for (int mf = 0; mf < 4; ++mf) {
          const float p0 = fast_exp2(fmaf(st[mf][nf][0], LOG2E, -ml2[nf]));
          const float p1 = fast_exp2(fmaf(st[mf][nf][1], LOG2E, -ml2[nf]));
          const float p2 = fast_exp2(fmaf(st[mf][nf][2], LOG2E, -ml2[nf]));
          const float p3 = fast_exp2(fmaf(st[mf][nf][3], LOG2E, -ml2[nf]));
          uint2v w;
          w.x = cvtpk(p0, p1);
          w.y = cvtpk(p2, p3);
          *reinterpret_cast<uint2v*>(
              pw + KSWZ(l15, mf * 32 + g * 8)) = w;
        }
#pragma unroll
        for (int ks = 0; ks < 2; ++ks) {
          bf16x8 pf = __builtin_bit_cast(bf16x8,
              *reinterpret_cast<const ushort8v*>(
                  pw + KSWZ(l15, ks * 64 + g * 16)));
          bf16x8 vt[4];
#pragma unroll
          for (int nd = 0; nd < 4; ++nd)
            vt[nd] = __builtin_bit_cast(bf16x8,
                *reinterpret_cast<const ushort8v*>(
                    vb + KSWZ(nd * 16 + l15, ks * 64 + g * 16)));
#pragma unroll
          for (int nd = 0; nd < 4; ++nd)
            oacc[nf][nd] = __builtin_amdgcn_mfma_f32_16x16x32_bf16(
                vt[nd], pf, oacc[nf][nd], 0, 0, 0);
          lacc[nf] = __builtin_amdgcn_mfma_f32_16x16x32_bf16(
              ones_f, pf, lacc[nf], 0, 0, 0);
        }
      }
    }
  }

  // ---- epilogue: normalize per-lane (col=tq), store O^T -> Og[t][c]
#pragma unroll
  for (int nf = 0; nf < 2; ++nf) {
    const float invl = 1.f / lacc[nf][0];
    const int t = q0 + wq0 + nf * 16 + l15;
#pragma unroll
    for (int nd = 0; nd < 4; ++nd) {
      uint2v o;
      o.x = cvtpk(oacc[nf][nd][0] * invl, oacc[nf][nd][1] * invl);
      o.y = cvtpk(oacc[nf][nd][2] * invl, oacc[nf][nd][3] * invl);
      *reinterpret_cast<uint2v*>(
          &Og[((size_t)(b_ * T_SEQ + t)) * C_EMB + h_ * 64 + nd * 16 + g * 4]) = o;
    }
  }
}

// ---------------------------------------------------------------- launch
extern "C" void kernel_launch(void* const* d_in, const int* in_sizes, int n_in,
                              void* d_out, int out_size, void* d_ws, size_t ws_size,
                              hipStream_t stream) {
  const float* x = (const float*)d_in[0];
  const float* w_attn = (const float*)d_in[1];
  const float* b_attn = (const float*)d_in[2];
  const float* w_proj = (const float*)d_in[3];
  const float* b_proj = (const float*)d_in[4];
  float* out = (float*)d_out;

  char* ws = (char*)d_ws;
  size_t off = 0;
  auto carve = [&](size_t bytes) -> void* {
    void* p = ws + off;
    off += (bytes + 255) & ~(size_t)255;
    return p;
  };
  // xbf/wab/wpb must stay contiguous (cvt_all_bf16 writes one range)
  unsigned short* xbf = (unsigned short*)carve((size_t)M_TOK * C_EMB * 2);
  unsigned short* wab = (unsigned short*)carve((size_t)N_QKV * C_EMB * 2);
  unsigned short* wpb = (unsigned short*)carve((size_t)C_EMB * C_EMB * 2);
  unsigned short* Qb = (unsigned short*)carve((size_t)B_SZ * NH_ * T_SEQ * HS_ * 2);
  unsigned short* Kb = (unsigned short*)carve((size_t)B_SZ * NH_ * T_SEQ * HS_ * 2);
  unsigned short* Vtb = (unsigned short*)carve((size_t)B_SZ * NH_ * T_SEQ * HS_ * 2);
  unsigned short* Ob = (unsigned short*)carve((size_t)M_TOK * C_EMB * 2);

  cvt_all_bf16<<<4224, 256, 0, stream>>>(x, w_attn, w_proj, xbf);

  gemm_bt_kernel<0, 128, 128><<<dim3(N_QKV / 128, M_TOK / 128), 256, 0, stream>>>(
      xbf, wab, b_attn, Qb, Kb, Vtb, nullptr, C_EMB, N_QKV);

  flash_kernel<<<dim3(768), 256, 0, stream>>>(Qb, Kb, Vtb, Ob);

  gemm_bt_kernel<1, 64, 128><<<dim3(C_EMB / 128, M_TOK / 64), 256, 0, stream>>>(
      Ob, wpb, b_proj, nullptr, nullptr, nullptr, out, C_EMB, C_EMB);
}